// Round 4
// baseline (357.555 us; speedup 1.0000x reference)
//
#include <hip/hip_runtime.h>
#include <cmath>

#define B_ 16
#define T_ 2048
#define NK 64
#define NH 128
#define NP 10000
#define ITEMS_PER_B 528            /* sum_{tile=0}^{31} (tile+1) */
#define N_ITEMS (B_ * ITEMS_PER_B) /* 8448 wave items */

/* ws layout (float offsets). Total ~9.45 MB. */
#define AHI_F 0        /* 640000 ushort (A hi-plane bf16)  = 320000 f */
#define ALO_F 320000   /* 640000 ushort (A lo-plane bf16)  = 320000 f */
#define NLAM_F 640000  /* 32768 f : -exp(kc.lam_w + b) per (b,t) */
#define GG_F  672768   /* 32768 f : sigmoid guess */
#define SS_F  705536   /* 32768 f : sigmoid slip  */
#define CNT_F 738304   /* 512 int : per-(b,tile) arrival counters */
#define PART_F 738816  /* 8448 * 192 f : per-item partials (num,den,total) */

typedef __attribute__((ext_vector_type(8))) short bf16x8;
typedef __attribute__((ext_vector_type(4))) float f32x4;
typedef __attribute__((ext_vector_type(4))) unsigned short us4;

__device__ __forceinline__ unsigned short f2bf(float x) {  // RNE fp32->bf16
  unsigned u = __float_as_uint(x);
  u += 0x7FFFu + ((u >> 16) & 1u);
  return (unsigned short)(u >> 16);
}

// ---------------- prep: A -> bf16 hi/lo planes; per-(b,t) lam/guess/slip; zero counters
__global__ __launch_bounds__(256) void prep(
    const int* __restrict__ pseq, const float* __restrict__ A,
    const float* __restrict__ kcw,
    const float* __restrict__ lam_w, const float* __restrict__ lam_b,
    const float* __restrict__ guess_w, const float* __restrict__ guess_b,
    const float* __restrict__ slip_w, const float* __restrict__ slip_b,
    float* __restrict__ ws) {
  const int tid = threadIdx.x, bid = blockIdx.x;
  if (bid == 0) {  // zero the 512 arrival counters
    ((int*)(ws + CNT_F))[tid] = 0;
    ((int*)(ws + CNT_F))[tid + 256] = 0;
  }
  // A (fp32) -> hi/lo bf16 planes, float4-granular grid-stride
  us4* hi4 = (us4*)(ws + AHI_F);
  us4* lo4 = (us4*)(ws + ALO_F);
  const float4* A4 = (const float4*)A;
  for (int i = bid * 256 + tid; i < NP * NK / 4; i += 512 * 256) {
    float4 v = A4[i];
    us4 h, l; float e;
    h.x = f2bf(v.x); e = v.x - __uint_as_float((unsigned)h.x << 16); l.x = f2bf(e);
    h.y = f2bf(v.y); e = v.y - __uint_as_float((unsigned)h.y << 16); l.y = f2bf(e);
    h.z = f2bf(v.z); e = v.z - __uint_as_float((unsigned)h.z << 16); l.z = f2bf(e);
    h.w = f2bf(v.w); e = v.w - __uint_as_float((unsigned)h.w << 16); l.w = f2bf(e);
    hi4[i] = h; lo4[i] = l;
  }
  // fp32-exact per-(b,t) heads (blocks 0..127 cover all 32768 t's)
  if (bid < 128) {
    __shared__ float wvec[3][NK];
    if (tid < 3 * NK) {
      int vec = tid >> 6, k = tid & 63;
      const float* wv = (vec == 0) ? lam_w : (vec == 1 ? guess_w : slip_w);
      float acc = 0.f;
      #pragma unroll 8
      for (int h = 0; h < NH; ++h) acc = fmaf(kcw[k * NH + h], wv[h], acc);
      wvec[vec][k] = acc;
    }
    __syncthreads();
    const int tg = bid * 256 + tid;                 // [0, 32768)
    const float* xr = A + ((size_t)pseq[tg] << 6);
    float aL = 0.f, aG = 0.f, aS = 0.f;
    #pragma unroll
    for (int k = 0; k < NK; ++k) {
      float xv = xr[k];
      aL = fmaf(xv, wvec[0][k], aL);
      aG = fmaf(xv, wvec[1][k], aG);
      aS = fmaf(xv, wvec[2][k], aS);
    }
    ws[NLAM_F + tg] = -__expf(aL + lam_b[0]);
    ws[GG_F + tg]   = 1.f / (1.f + __expf(-(aG + guess_b[0])));
    ws[SS_F + tg]   = 1.f / (1.f + __expf(-(aS + slip_b[0])));
  }
}

// ---------------- main: MFMA sim tiles + in-register suffix scan + fused tail combine
// Wave item = (b, tile, chunk): 64 t x 64 s. sim via hi/lo-split bf16 MFMA (hh+hl+lh).
// C layout (m89-verified): col = lane&15 (t), row = 4*(lane>>4)+reg (s).
__global__ __launch_bounds__(256) void mainmfma(
    const float* __restrict__ y, const int* __restrict__ pseq,
    float* __restrict__ ws, float* __restrict__ out) {
  __shared__ float yl[4][64];
  const int lane = threadIdx.x & 63;
  const int wv = __builtin_amdgcn_readfirstlane(threadIdx.x >> 6);
  const int item = blockIdx.x * 4 + wv;
  const int b = item / ITEMS_PER_B;
  const int r0 = item - b * ITEMS_PER_B;
  int tile = (int)((sqrtf(8.f * (float)r0 + 1.f) - 1.f) * 0.5f);
  while ((tile + 1) * (tile + 2) / 2 <= r0) ++tile;
  while (tile * (tile + 1) / 2 > r0) --tile;
  const int chunk = r0 - tile * (tile + 1) / 2;
  const int t0 = tile << 6, s0 = chunk << 6;
  const int base = b * T_;
  const int c = lane & 15, g = lane >> 4;

  int ps[4], pt[4];
  #pragma unroll
  for (int f = 0; f < 4; ++f) {
    ps[f] = pseq[base + s0 + 16 * f + c];   // A-frag rows: s = s0+16f+c
    pt[f] = pseq[base + t0 + 16 * f + c];   // B-frag rows: t = t0+16f+c
  }
  const unsigned short* Ah = (const unsigned short*)(ws + AHI_F);
  const unsigned short* Al = (const unsigned short*)(ws + ALO_F);
  bf16x8 ah[4][2], am[4][2], bh[4][2], bm[4][2];
  #pragma unroll
  for (int f = 0; f < 4; ++f) {
    #pragma unroll
    for (int ks = 0; ks < 2; ++ks) {
      const int ko = 8 * g + 32 * ks;       // lane k-chunk
      ah[f][ks] = *(const bf16x8*)(Ah + (size_t)ps[f] * 64 + ko);
      am[f][ks] = *(const bf16x8*)(Al + (size_t)ps[f] * 64 + ko);
      bh[f][ks] = *(const bf16x8*)(Ah + (size_t)pt[f] * 64 + ko);
      bm[f][ks] = *(const bf16x8*)(Al + (size_t)pt[f] * 64 + ko);
    }
  }
  f32x4 acc[4][4] = {};
  #pragma unroll
  for (int ks = 0; ks < 2; ++ks)
    #pragma unroll
    for (int fi = 0; fi < 4; ++fi)
      #pragma unroll
      for (int fj = 0; fj < 4; ++fj) {
        acc[fi][fj] = __builtin_amdgcn_mfma_f32_16x16x32_bf16(ah[fi][ks], bh[fj][ks], acc[fi][fj], 0, 0, 0);
        acc[fi][fj] = __builtin_amdgcn_mfma_f32_16x16x32_bf16(ah[fi][ks], bm[fj][ks], acc[fi][fj], 0, 0, 0);
        acc[fi][fj] = __builtin_amdgcn_mfma_f32_16x16x32_bf16(am[fi][ks], bh[fj][ks], acc[fi][fj], 0, 0, 0);
      }

  yl[wv][lane] = y[base + s0 + lane];       // per-wave y tile (same-wave RAW, no barrier)
  float yy[4][4];
  #pragma unroll
  for (int fi = 0; fi < 4; ++fi) {
    float4 t4 = *(const float4*)&yl[wv][16 * fi + 4 * g];
    yy[fi][0] = t4.x; yy[fi][1] = t4.y; yy[fi][2] = t4.z; yy[fi][3] = t4.w;
  }

  const bool diag = (chunk == tile);
  float* po = ws + PART_F + (size_t)item * 192;

  #pragma unroll
  for (int fj = 0; fj < 4; ++fj) {
    const float nl = ws[NLAM_F + base + t0 + 16 * fj + c];  // -lam for this column
    float sm[4][4], pp[4][4], S[4], ft[4];
    #pragma unroll
    for (int fi = 0; fi < 4; ++fi) {
      f32x4 v = acc[fi][fj];
      if (diag) {                         // strictly-past mask: s-row < t-col
        #pragma unroll
        for (int rr = 0; rr < 4; ++rr)
          if (16 * fi + 4 * g + rr >= 16 * fj + c) v[rr] = 0.f;
      }
      sm[fi][0] = v.x; sm[fi][1] = v.y; sm[fi][2] = v.z; sm[fi][3] = v.w;
      float p3 = v.w, p2 = p3 + v.z, p1 = p2 + v.y, p0 = p1 + v.x;  // in-lane suffix
      pp[fi][0] = p0; pp[fi][1] = p1; pp[fi][2] = p2; pp[fi][3] = p3;
      float u16 = __shfl_xor(p0, 16);     // quad butterfly (rows 4g..4g+3 groups)
      float pr = p0 + u16;
      float u32 = __shfl_xor(pr, 32);
      ft[fi] = pr + u32;                  // fragment total (all 16 rows)
      S[fi] = ((g & 1) ? 0.f : u16) + ((g < 2) ? u32 : 0.f);  // suffix of higher groups
    }
    const float F2 = ft[3], F1 = F2 + ft[2], F0 = F1 + ft[1];
    const float Fv[4] = {F0, F1, F2, 0.f};  // suffix of higher fragments
    float num = 0.f, den = 0.f;
    #pragma unroll
    for (int fi = 0; fi < 4; ++fi) {
      const float SF = S[fi] + Fv[fi];
      #pragma unroll
      for (int rr = 0; rr < 4; ++rr) {
        const float dl = pp[fi][rr] + SF;   // local delta (incl. self)
        const float e = __expf(nl * dl);
        const float w = sm[fi][rr] * e;
        den += w;
        num = fmaf(yy[fi][rr], w, num);
      }
    }
    num += __shfl_xor(num, 16); num += __shfl_xor(num, 32);
    den += __shfl_xor(den, 16); den += __shfl_xor(den, 32);
    const float tot = Fv[0] + ft[0];
    if (g == 0) {
      po[16 * fj + c] = num;
      po[64 + 16 * fj + c] = den;
      po[128 + 16 * fj + c] = tot;
    }
  }

  // fused tail: last-arriving chunk of this (b,tile) combines + epilogue
  __threadfence();
  int old = 0;
  if (lane == 0) old = atomicAdd((int*)(ws + CNT_F) + (b * 32 + tile), 1);
  old = __shfl(old, 0);
  if (old == tile) {
    __threadfence();                      // acquire: see all chunks' partials
    const int t = t0 + lane;
    const float nl = ws[NLAM_F + base + t];
    const int ibase = b * ITEMS_PER_B + tile * (tile + 1) / 2;
    float N = 0.f, D = 0.f, Roff = 0.f;
    for (int cc = tile; cc >= 0; --cc) {  // descending s
      const float* p = ws + PART_F + (size_t)(ibase + cc) * 192;
      const float e = __expf(nl * Roff);
      N = fmaf(p[lane], e, N);
      D = fmaf(p[64 + lane], e, D);
      Roff += p[128 + lane];
    }
    const float gv = ws[GG_F + base + t];
    const float sv = ws[SS_F + base + t];
    const float h = N / (D + 1e-6f);
    float yh = h * (1.f - sv) + (1.f - h) * gv;
    out[base + t] = fminf(fmaxf(yh, 0.01f), 0.99f);
  }
}

extern "C" void kernel_launch(void* const* d_in, const int* in_sizes, int n_in,
                              void* d_out, int out_size, void* d_ws, size_t ws_size,
                              hipStream_t stream) {
  const float* y    = (const float*)d_in[0];
  const int*   pseq = (const int*)  d_in[1];
  const float* A    = (const float*)d_in[2];
  const float* kcw  = (const float*)d_in[3];
  const float* lw   = (const float*)d_in[4];
  const float* lb   = (const float*)d_in[5];
  const float* gw   = (const float*)d_in[6];
  const float* gb   = (const float*)d_in[7];
  const float* sw   = (const float*)d_in[8];
  const float* sb   = (const float*)d_in[9];
  float* out = (float*)d_out;
  float* ws  = (float*)d_ws;   // needs ~9.45 MB

  prep<<<512, 256, 0, stream>>>(pseq, A, kcw, lw, lb, gw, gb, sw, sb, ws);
  mainmfma<<<N_ITEMS / 4, 256, 0, stream>>>(y, pseq, ws, out);
}

// Round 5
// 121.135 us; speedup vs baseline: 2.9517x; 2.9517x over previous
//
#include <hip/hip_runtime.h>

#define B_ 16
#define T_ 2048
#define NP 10000
#define NH 128

/* ws float offsets. XF: frag-ready bf16 hi/lo planes of X[b,t]=A[pseq[b,t]] (8MB) */
#define XF_F   0
#define NLAM_F 2097152
#define GG_F   2129920
#define SS_F   2162688

typedef __attribute__((ext_vector_type(8))) short bf16x8;
typedef __attribute__((ext_vector_type(4))) float f32x4;

__device__ __forceinline__ unsigned short f2bf(float x) {  // RNE fp32->bf16
  unsigned u = __float_as_uint(x);
  u += 0x7FFFu + ((u >> 16) & 1u);
  return (unsigned short)(u >> 16);
}
// shorts offset of frag slot: (b, 16-row group R, plane hi/lo, K-half ks)
__device__ __forceinline__ size_t xfbase(int b, int R, int plane, int ks) {
  return ((((size_t)b * 128 + R) * 2 + plane) * 2 + ks) * 512;
}

// ---- prep: X -> frag-ready bf16 hi/lo; per-(b,t) -lam / guess / slip (fp32 exact)
__global__ __launch_bounds__(256) void prep(
    const int* __restrict__ pseq, const float* __restrict__ A,
    const float* __restrict__ kcw,
    const float* __restrict__ lam_w, const float* __restrict__ lam_b,
    const float* __restrict__ guess_w, const float* __restrict__ guess_b,
    const float* __restrict__ slip_w, const float* __restrict__ slip_b,
    float* __restrict__ ws) {
  const int tid = threadIdx.x, bid = blockIdx.x;
  const int lane = tid & 63, wv = tid >> 6;
  {  // wave W -> (b, R, ks). Lane l: row R*16+(l&15), elems ks*32+(l>>4)*8 .. +8
    const int W = bid * 4 + wv;            // [0, 4096)
    const int b = W >> 8, rem = W & 255, R = rem >> 1, ks = rem & 1;
    const int row = (R << 4) + (lane & 15), gp = lane >> 4;
    const float* src = A + (size_t)pseq[b * T_ + row] * 64 + ks * 32 + gp * 8;
    float4 v0 = *(const float4*)src;
    float4 v1 = *(const float4*)(src + 4);
    float vv[8] = {v0.x, v0.y, v0.z, v0.w, v1.x, v1.y, v1.z, v1.w};
    union { unsigned short s[8]; bf16x8 v; } H, L;
    #pragma unroll
    for (int i = 0; i < 8; ++i) {
      H.s[i] = f2bf(vv[i]);
      float e = vv[i] - __uint_as_float((unsigned)H.s[i] << 16);
      L.s[i] = f2bf(e);
    }
    unsigned short* X = (unsigned short*)ws;
    *(bf16x8*)(X + xfbase(b, R, 0, ks) + lane * 8) = H.v;
    *(bf16x8*)(X + xfbase(b, R, 1, ks) + lane * 8) = L.v;
  }
  if (bid < 128) {  // heads: 32768 (b,t) pairs
    __shared__ float wvec[3][64];
    if (tid < 192) {
      int vec = tid >> 6, k = tid & 63;
      const float* wvp = (vec == 0) ? lam_w : (vec == 1 ? guess_w : slip_w);
      float acc = 0.f;
      #pragma unroll 8
      for (int h = 0; h < NH; ++h) acc = fmaf(kcw[k * NH + h], wvp[h], acc);
      wvec[vec][k] = acc;
    }
    __syncthreads();
    const int tg = bid * 256 + tid;
    const float* xr = A + ((size_t)pseq[tg] << 6);
    float aL = 0.f, aG = 0.f, aS = 0.f;
    #pragma unroll
    for (int k = 0; k < 64; ++k) {
      float xv = xr[k];
      aL = fmaf(xv, wvec[0][k], aL);
      aG = fmaf(xv, wvec[1][k], aG);
      aS = fmaf(xv, wvec[2][k], aS);
    }
    ws[NLAM_F + tg] = -__expf(aL + lam_b[0]);
    ws[GG_F + tg]   = 1.f / (1.f + __expf(-(aG + guess_b[0])));
    ws[SS_F + tg]   = 1.f / (1.f + __expf(-(aS + slip_b[0])));
  }
}

// ---- main: block = (b,tile); 8 waves own descending chunk ranges; in-register
// cross-chunk fold (exp-rescale identity); LDS+syncthreads wave combine; no atomics.
__global__ __launch_bounds__(512, 2) void mainK(
    const float* __restrict__ y, float* __restrict__ ws,
    float* __restrict__ out) {
  __shared__ float part[8][3][64];
  const int tid = threadIdx.x, bid = blockIdx.x;
  const int lane = tid & 63;
  const int wv = __builtin_amdgcn_readfirstlane(tid >> 6);
  const int u = bid & 255, half = bid >> 8;
  const int b = u >> 4, kk = u & 15;
  const int tile = half ? kk : 31 - kk;     // heavy tiles in first dispatch round
  const int t0 = tile << 6, base = b * T_;
  const int c = lane & 15, g = lane >> 4;
  const unsigned short* X = (const unsigned short*)ws;

  float nl[4];
  #pragma unroll
  for (int fj = 0; fj < 4; ++fj) nl[fj] = ws[NLAM_F + base + t0 + 16 * fj + c];

  const int nchunks = tile + 1;
  const int nc = (nchunks + 7) >> 3;
  const int cLo = wv * nc;
  const int cHi = min(cLo + nc, nchunks);

  float NA[4] = {0,0,0,0}, DA[4] = {0,0,0,0}, RA[4] = {0,0,0,0};

  for (int cc = cHi - 1; cc >= cLo; --cc) {   // descending s
    const bool diag = (cc == tile);
    float yy[4][4];
    #pragma unroll
    for (int fi = 0; fi < 4; ++fi) {
      float4 t4 = *(const float4*)(y + base + (cc << 6) + 16 * fi + 4 * g);
      yy[fi][0] = t4.x; yy[fi][1] = t4.y; yy[fi][2] = t4.z; yy[fi][3] = t4.w;
    }
    #pragma unroll
    for (int fjh = 0; fjh < 2; ++fjh) {       // fj in halves: caps live VGPRs
      bf16x8 bh[2][2], bm[2][2];
      #pragma unroll
      for (int j2 = 0; j2 < 2; ++j2)
        #pragma unroll
        for (int ks = 0; ks < 2; ++ks) {
          const int R = tile * 4 + 2 * fjh + j2;
          bh[j2][ks] = *(const bf16x8*)(X + xfbase(b, R, 0, ks) + lane * 8);
          bm[j2][ks] = *(const bf16x8*)(X + xfbase(b, R, 1, ks) + lane * 8);
        }
      f32x4 acc[4][2] = {};
      #pragma unroll
      for (int ks = 0; ks < 2; ++ks) {
        bf16x8 ah[4], am[4];
        #pragma unroll
        for (int fi = 0; fi < 4; ++fi) {
          const int R = cc * 4 + fi;
          ah[fi] = *(const bf16x8*)(X + xfbase(b, R, 0, ks) + lane * 8);
          am[fi] = *(const bf16x8*)(X + xfbase(b, R, 1, ks) + lane * 8);
        }
        #pragma unroll
        for (int fi = 0; fi < 4; ++fi)
          #pragma unroll
          for (int j2 = 0; j2 < 2; ++j2) {    // hi/lo split: hh + hl + lh (exact-ish)
            acc[fi][j2] = __builtin_amdgcn_mfma_f32_16x16x32_bf16(ah[fi], bh[j2][ks], acc[fi][j2], 0, 0, 0);
            acc[fi][j2] = __builtin_amdgcn_mfma_f32_16x16x32_bf16(ah[fi], bm[j2][ks], acc[fi][j2], 0, 0, 0);
            acc[fi][j2] = __builtin_amdgcn_mfma_f32_16x16x32_bf16(am[fi], bh[j2][ks], acc[fi][j2], 0, 0, 0);
          }
      }
      #pragma unroll
      for (int j2 = 0; j2 < 2; ++j2) {
        const int fj = 2 * fjh + j2;
        float sm[4][4], pp[4][4], S[4], ft[4];
        #pragma unroll
        for (int fi = 0; fi < 4; ++fi) {      // C layout: col=c (t), row=4g+rr (s)
          f32x4 v = acc[fi][j2];
          if (diag) {
            #pragma unroll
            for (int rr = 0; rr < 4; ++rr)
              if (16 * fi + 4 * g + rr >= 16 * fj + c) v[rr] = 0.f;
          }
          sm[fi][0]=v.x; sm[fi][1]=v.y; sm[fi][2]=v.z; sm[fi][3]=v.w;
          float p3 = v.w, p2 = p3 + v.z, p1 = p2 + v.y, p0 = p1 + v.x;
          pp[fi][0]=p0; pp[fi][1]=p1; pp[fi][2]=p2; pp[fi][3]=p3;
          float u16 = __shfl_xor(p0, 16);     // quad butterfly over row-groups
          float pr = p0 + u16;
          float u32 = __shfl_xor(pr, 32);
          ft[fi] = pr + u32;                  // fragment total
          S[fi] = ((g & 1) ? 0.f : u16) + ((g < 2) ? u32 : 0.f); // higher-group suffix
        }
        const float F2 = ft[3], F1 = F2 + ft[2], F0 = F1 + ft[1];
        const float Fv[4] = {F0, F1, F2, 0.f};
        float num = 0.f, den = 0.f;
        #pragma unroll
        for (int fi = 0; fi < 4; ++fi) {
          const float SF = S[fi] + Fv[fi];
          #pragma unroll
          for (int rr = 0; rr < 4; ++rr) {
            const float dl = pp[fi][rr] + SF;       // local suffix incl. self
            const float e = __expf(nl[fj] * dl);
            const float w = sm[fi][rr] * e;
            den += w;
            num = fmaf(yy[fi][rr], w, num);
          }
        }
        num += __shfl_xor(num, 16); num += __shfl_xor(num, 32);
        den += __shfl_xor(den, 16); den += __shfl_xor(den, 32);
        const float tot = Fv[0] + ft[0];
        const float e = __expf(nl[fj] * RA[fj]);    // fold chunk into wave accum
        NA[fj] = fmaf(num, e, NA[fj]);
        DA[fj] = fmaf(den, e, DA[fj]);
        RA[fj] += tot;
      }
    }
  }

  if (g == 0) {
    #pragma unroll
    for (int fj = 0; fj < 4; ++fj) {
      part[wv][0][16 * fj + c] = NA[fj];
      part[wv][1][16 * fj + c] = DA[fj];
      part[wv][2][16 * fj + c] = RA[fj];
    }
  }
  __syncthreads();

  if (wv == 0) {   // fold 8 wave ranges (descending: wave 7 = highest s), epilogue
    const int t = t0 + lane;
    const float nlt = ws[NLAM_F + base + t];
    float N = 0.f, D = 0.f, Roff = 0.f;
    #pragma unroll
    for (int w = 7; w >= 0; --w) {
      const float e = __expf(nlt * Roff);
      N = fmaf(part[w][0][lane], e, N);
      D = fmaf(part[w][1][lane], e, D);
      Roff += part[w][2][lane];
    }
    const float gv = ws[GG_F + base + t];
    const float sv = ws[SS_F + base + t];
    const float h = N / (D + 1e-6f);
    float yh = h * (1.f - sv) + (1.f - h) * gv;
    out[base + t] = fminf(fmaxf(yh, 0.01f), 0.99f);
  }
}

extern "C" void kernel_launch(void* const* d_in, const int* in_sizes, int n_in,
                              void* d_out, int out_size, void* d_ws, size_t ws_size,
                              hipStream_t stream) {
  const float* y    = (const float*)d_in[0];
  const int*   pseq = (const int*)  d_in[1];
  const float* A    = (const float*)d_in[2];
  const float* kcw  = (const float*)d_in[3];
  const float* lw   = (const float*)d_in[4];
  const float* lb   = (const float*)d_in[5];
  const float* gw   = (const float*)d_in[6];
  const float* gb   = (const float*)d_in[7];
  const float* sw   = (const float*)d_in[8];
  const float* sb   = (const float*)d_in[9];
  float* out = (float*)d_out;
  float* ws  = (float*)d_ws;   // ~8.8 MB used

  prep<<<1024, 256, 0, stream>>>(pseq, A, kcw, lw, lb, gw, gb, sw, sb, ws);
  mainK<<<512, 512, 0, stream>>>(y, ws, out);
}